// Round 7
// baseline (6613.469 us; speedup 1.0000x reference)
//
#include <hip/hip_runtime.h>
#include <hip/hip_bf16.h>
#include <cstdint>
#include <cstddef>

typedef __bf16 bf16_t;
typedef bf16_t bf16x8 __attribute__((ext_vector_type(8)));
typedef float  f32x4  __attribute__((ext_vector_type(4)));

#define TT    64
#define T_CTX 24
#define HOR   40
#define M     128     // nodes per block
#define GRID  128
#define NTH   1024    // 16 waves: waves 0-7 = nodes 0-63, 8-15 = nodes 64-127
#define SB    296     // A-buffer stride: raw(32)+h0(128)+h1(128)+pad(8); 592B, 16B-aligned

#define MFMA __builtin_amdgcn_mfma_f32_16x16x32_bf16

// ---- ws layout (bf16-element offsets; flag int at elem 0) ----
// E stream/slice: 52 frags = l0 [g][kt0..4] (kt0=folded raw) + l1 [g][kt0..7]
// D stream/slice: 60 frags = l0(20) + l1(32) + head(8);  X: 16 frags
#define O_PKE   16
#define O_PKD   (O_PKE + 212992)
#define O_PKX   (O_PKD + 245760)
#define O_BIAS  (O_PKX + 65536)
#define O_HEADP (O_BIAS + 2048)
#define O_B2    (O_HEADP + 512)

struct Ptrs { const void* q[29]; };

__device__ __forceinline__ float sigm(float x) {
  return __builtin_amdgcn_rcpf(1.f + __expf(-x));
}
__device__ __forceinline__ float tanh_(float x) {
  return 1.f - 2.f * __builtin_amdgcn_rcpf(1.f + __expf(2.f * x));
}
__device__ __forceinline__ unsigned pk2(float a, float b) {
  unsigned ua = __float_as_uint(a), ub = __float_as_uint(b);
  ua = (ua + 0x7fffu + ((ua >> 16) & 1u)) >> 16;
  ub = (ub + 0x7fffu + ((ub >> 16) & 1u)) >> 16;
  return ua | (ub << 16);
}
__device__ __forceinline__ float uplo(unsigned p){ return __uint_as_float(p << 16); }
__device__ __forceinline__ float uphi(unsigned p){ return __uint_as_float(p & 0xffff0000u); }

// ================= dtype detector (validated r2) =================
__global__ void detect_kernel(const unsigned short* __restrict__ wsrc, int* __restrict__ flag)
{
  int tid = threadIdx.x;
  int wild = 0;
  for (int i = tid; i < 256; i += 64) {
    unsigned short b = wsrc[i];
    float v  = __uint_as_float(((unsigned)b) << 16);
    float av = fabsf(v);
    unsigned e = (b >> 7) & 0xff;
    if (av > 1000.f || e == 0xff || (((b & 0x7fff) != 0) && av < 1e-9f)) wild++;
  }
  for (int off = 32; off; off >>= 1) wild += __shfl_down(wild, off, 64);
  if (tid == 0) flag[0] = (wild > 16) ? 1 : 0;
}

// ================= prep (identical stream layout to r6, validated) =================
__global__ void prep_kernel(Ptrs P, bf16_t* __restrict__ wb, const int* __restrict__ flag)
{
  const bool f32 = (flag[0] != 0);
  const int gtid = blockIdx.x * blockDim.x + threadIdx.x;
  const int gsz  = gridDim.x * blockDim.x;
  auto rd = [&](const void* src, int i) -> float {
    return f32 ? ((const float*)src)[i] : (float)((const bf16_t*)src)[i];
  };
  auto foldE = [&](int row, int c) -> float {
    float a = 0.f;
    for (int k = 0; k < 128; ++k) a += rd(P.q[4], row * 128 + k) * rd(P.q[3], k * 10 + c);
    return a;
  };
  auto foldD = [&](int row, int c) -> float {
    float a = 0.f;
    for (int k = 0; k < 128; ++k) a += rd(P.q[13], row * 256 + k) * rd(P.q[12], k * 10 + c);
    return a;
  };

  for (int i = gtid; i < 212992; i += gsz) {
    int w = i / 26624, r = i % 26624, f = r >> 9, e = r & 511;
    int ln = e >> 3, j = e & 7;
    int colk = ((ln >> 4) << 3) + j;
    float v;
    if (f < 20) {
      int g = f / 5, kt = f % 5;
      int row = g * 128 + w * 16 + (ln & 15);
      if (kt == 0) v = (colk < 10) ? foldE(row, colk) : 0.f;
      else         v = rd(P.q[5], row * 128 + (kt - 1) * 32 + colk);
    } else {
      int f2 = f - 20, g = f2 >> 3, kt = f2 & 7;
      int row = g * 128 + w * 16 + (ln & 15);
      v = (kt < 4) ? rd(P.q[8], row * 128 + kt * 32 + colk)
                   : rd(P.q[9], row * 128 + (kt - 4) * 32 + colk);
    }
    wb[O_PKE + i] = (bf16_t)v;
  }
  for (int i = gtid; i < 245760; i += gsz) {
    int w = i / 30720, r = i % 30720, f = r >> 9, e = r & 511;
    int ln = e >> 3, j = e & 7;
    int colk = ((ln >> 4) << 3) + j;
    float v;
    if (f < 20) {
      int g = f / 5, kt = f % 5;
      int row = g * 128 + w * 16 + (ln & 15);
      if (kt == 0) v = (colk < 10) ? foldD(row, colk) : 0.f;
      else         v = rd(P.q[14], row * 128 + (kt - 1) * 32 + colk);
    } else if (f < 52) {
      int f2 = f - 20, g = f2 >> 3, kt = f2 & 7;
      int row = g * 128 + w * 16 + (ln & 15);
      v = (kt < 4) ? rd(P.q[17], row * 128 + kt * 32 + colk)
                   : rd(P.q[18], row * 128 + (kt - 4) * 32 + colk);
    } else {
      int f2 = f - 52, h = f2 >> 2, kt = f2 & 3;
      int row = w * 16 + (ln & 15);
      v = rd(h ? P.q[25] : P.q[21], row * 128 + kt * 32 + colk);
    }
    wb[O_PKD + i] = (bf16_t)v;
  }
  for (int i = gtid; i < 65536; i += gsz) {
    int w = i >> 13, r = i & 8191, f = r >> 9, e = r & 511;
    int ln = e >> 3, j = e & 7;
    int colk = ((ln >> 4) << 3) + j;
    int g = f >> 2, kt = f & 3;
    int row = g * 128 + w * 16 + (ln & 15);
    wb[O_PKX + i] = (bf16_t)rd(P.q[13], row * 256 + 128 + kt * 32 + colk);
  }
  for (int i = gtid; i < 512; i += gsz) {
    wb[O_BIAS + i]        = (bf16_t)(rd(P.q[6],  i) + rd(P.q[7],  i));
    wb[O_BIAS + 512 + i]  = (bf16_t)(rd(P.q[10], i) + rd(P.q[11], i));
    wb[O_BIAS + 1024 + i] = (bf16_t)(rd(P.q[15], i) + rd(P.q[16], i));
    wb[O_BIAS + 1536 + i] = (bf16_t)(rd(P.q[19], i) + rd(P.q[20], i));
  }
  for (int i = gtid; i < 128; i += gsz) {
    wb[O_HEADP + i]       = (bf16_t)rd(P.q[22], i);
    wb[O_HEADP + 128 + i] = (bf16_t)rd(P.q[23], i);
    wb[O_HEADP + 256 + i] = (bf16_t)rd(P.q[26], i);
    wb[O_HEADP + 384 + i] = (bf16_t)rd(P.q[27], i);
  }
  if (gtid == 0) {
    wb[O_B2]     = (bf16_t)rd(P.q[24], 0);
    wb[O_B2 + 1] = (bf16_t)rd(P.q[28], 0);
  }
}

// ================= building blocks =================
template<int NF>
__device__ __forceinline__ void ldF(bf16x8 (&d)[NF], const bf16_t* __restrict__ pl, int f0) {
#pragma unroll
  for (int i = 0; i < NF; ++i) d[i] = *(const bf16x8*)(pl + (f0 + i) * 512);
}

// ac[mt] += A(LDS, row = mt*16+l, cols colofs + kt*32 + q*8) @ bf^T
template<int NKT>
__device__ __forceinline__ void gpass(f32x4 (&ac)[4], const bf16_t* __restrict__ As,
                                      const bf16x8 (&bf)[NKT], int l, int q) {
#pragma unroll
  for (int kt = 0; kt < NKT; ++kt) {
#pragma unroll
    for (int mt = 0; mt < 4; ++mt) {
      bf16x8 a = *(const bf16x8*)(As + (mt * 16 + l) * SB + kt * 32 + q * 8);
      ac[mt] = MFMA(a, bf[kt], ac[mt], 0, 0, 0);
    }
  }
}

__device__ __forceinline__ void cell_up(f32x4 (&acc)[4][4], float (&c)[16],
                                        bf16_t* __restrict__ dst,  // s_buf + rowbase*SB + colofs
                                        const bf16_t* __restrict__ bias, int jc, int q)
{
  const float bi  = (float)bias[jc];
  const float bf_ = (float)bias[128 + jc];
  const float bg  = (float)bias[256 + jc];
  const float bo  = (float)bias[384 + jc];
#pragma unroll
  for (int mt = 0; mt < 4; ++mt) {
#pragma unroll
    for (int r = 0; r < 4; ++r) {
      float gi = acc[0][mt][r] + bi;
      float gf = acc[1][mt][r] + bf_;
      float gg = acc[2][mt][r] + bg;
      float go = acc[3][mt][r] + bo;
      float cn = sigm(gf) * c[mt * 4 + r] + sigm(gi) * tanh_(gg);
      float hh = sigm(go) * tanh_(cn);
      c[mt * 4 + r] = cn;
      dst[(mt * 16 + q * 4 + r) * SB + jc] = (bf16_t)hh;
    }
  }
}

#define ZACC(A) _Pragma("unroll") for (int _g = 0; _g < 4; ++_g) \
                _Pragma("unroll") for (int _m = 0; _m < 4; ++_m) A[_g][_m] = f32x4{0.f,0.f,0.f,0.f};

// ================= persistent LSTM kernel =================
template<typename T>
__global__ __launch_bounds__(NTH, 1) void lstm_persist(
    const T* __restrict__ x, const T* __restrict__ coords, const T* __restrict__ env,
    const bf16_t* __restrict__ w, const int* __restrict__ flag, T* __restrict__ out)
{
  const bool want_f32 = (sizeof(T) == 4);
  if ((flag[0] != 0) != want_f32) return;

  __shared__ __align__(16) bf16_t s_buf[M * SB];   // [raw32 | h0 | h1] per node-row
  __shared__ __align__(16) bf16_t s_bias[2048];
  __shared__ float s_red[2 * M];
  __shared__ float s_xc[M];

  const int tid  = threadIdx.x;
  const int wid  = tid >> 6;          // 0..15
  const int lane = tid & 63;
  const int l    = tid & 15;
  const int q    = (tid & 63) >> 4;
  const int uw   = wid & 7;           // unit-slice (twin waves share streams)
  const int rowbase = (wid >> 3) * 64;
  const int jc   = uw * 16 + l;
  const int node0 = blockIdx.x * M;

  const bf16_t* plE = w + O_PKE + uw * 26624 + lane * 8;
  const bf16_t* plD = w + O_PKD + uw * 30720 + lane * 8;
  const bf16_t* plX = w + O_PKX + uw * 8192  + lane * 8;

  bf16_t* Al0 = s_buf + rowbase * SB;        // l0 A: cols 0..159
  bf16_t* Al1 = Al0 + 32;                    // l1 A: cols 32..287
  bf16_t* Ahd = Al0 + 160;                   // h1:   cols 160..287

  for (int i = tid; i < 2048; i += NTH) s_bias[i] = w[O_BIAS + i];
  for (int i = tid; i < M * SB; i += NTH) s_buf[i] = (bf16_t)0.f;

  const T* xb = x   + (size_t)(node0 + tid) * TT;     // valid reads only for tid<128
  const T* eb = env + (size_t)(node0 + tid) * 7 * TT;
  float cx = 0.f, cy = 0.f, pfx = 0.f;
  float pfe[7];
#pragma unroll
  for (int e = 0; e < 7; ++e) pfe[e] = 0.f;
  if (tid < M) {
    cx  = (float)coords[(size_t)(node0 + tid) * 2 + 0];
    cy  = (float)coords[(size_t)(node0 + tid) * 2 + 1];
    pfx = (float)xb[0];
#pragma unroll
    for (int e = 0; e < 7; ++e) pfe[e] = (float)eb[e * TT];
  }

  float c0[16], c1[16];
#pragma unroll
  for (int i = 0; i < 16; ++i) { c0[i] = 0.f; c1[i] = 0.f; }

  bf16x8 g0[5]; ldF<5>(g0, plE, 0);
  bf16x8 bX0[4];
  __syncthreads();                                    // zeros done
  if (tid < M) {
    s_buf[tid * SB + 0] = (bf16_t)pfx;
    s_buf[tid * SB + 1] = (bf16_t)cx;
    s_buf[tid * SB + 2] = (bf16_t)cy;
#pragma unroll
    for (int e = 0; e < 7; ++e) s_buf[tid * SB + 3 + e] = (bf16_t)pfe[e];
  }
  __syncthreads();                                    // raw0 ready; g0 drained

  // ================= encoder =================
#pragma unroll 1
  for (int t = 0; t < T_CTX; ++t) {
    f32x4 acc[4][4]; ZACC(acc)
    bf16x8 g1[5]; ldF<5>(g1, plE, 5);
    gpass<5>(acc[0], Al0, g0, l, q);
    bf16x8 g2[5]; ldF<5>(g2, plE, 10);
    gpass<5>(acc[1], Al0, g1, l, q);
    bf16x8 g3[5]; ldF<5>(g3, plE, 15);
    gpass<5>(acc[2], Al0, g2, l, q);
    bf16x8 u0[4]; ldF<4>(u0, plE, 20);                // l1 (g0,kt0..3)
    gpass<5>(acc[3], Al0, g3, l, q);
    __syncthreads();                                  // Ba: l0 reads done
    cell_up(acc, c0, Al0 - rowbase * SB + rowbase * SB + 32, s_bias, jc, q);  // h0 cols 32..
    bf16x8 u1[4]; ldF<4>(u1, plE, 24);                // (g0,kt4..7)
    __syncthreads();                                  // Bb: h0 ready
    ZACC(acc)
    gpass<4>(acc[0], Al1, u0, l, q);
    bf16x8 u2[4]; ldF<4>(u2, plE, 28);
    gpass<4>(acc[0], Al1 + 128, u1, l, q);
    bf16x8 u3[4]; ldF<4>(u3, plE, 32);
    gpass<4>(acc[1], Al1, u2, l, q);
    bf16x8 u4[4]; ldF<4>(u4, plE, 36);
    gpass<4>(acc[1], Al1 + 128, u3, l, q);
    bf16x8 u5[4]; ldF<4>(u5, plE, 40);
    gpass<4>(acc[2], Al1, u4, l, q);
    bf16x8 u6[4]; ldF<4>(u6, plE, 44);
    if (tid < M) {
      if (t + 1 < T_CTX) pfx = (float)xb[t + 1];
#pragma unroll
      for (int e = 0; e < 7; ++e) pfe[e] = (float)eb[e * TT + t + 1];
    }
    gpass<4>(acc[2], Al1 + 128, u5, l, q);
    bf16x8 u7[4]; ldF<4>(u7, plE, 48);
    gpass<4>(acc[3], Al1, u6, l, q);
    if (t < T_CTX - 1) ldF<5>(g0, plE, 0);
    else               ldF<4>(bX0, plX, 0);
    gpass<4>(acc[3], Al1 + 128, u7, l, q);
    __syncthreads();                                  // Bc: l1 reads done
    cell_up(acc, c1, Al0 - rowbase * SB + rowbase * SB + 160, s_bias + 512, jc, q);  // h1
    if (tid < M && t < T_CTX - 1) {
      s_buf[tid * SB + 0] = (bf16_t)pfx;
#pragma unroll
      for (int e = 0; e < 7; ++e) s_buf[tid * SB + 3 + e] = (bf16_t)pfe[e];
    }
    __syncthreads();                                  // Bd: h1 + raw ready
  }

  // ---- enc-term gemm (K=128) -> geh registers ----
  uint2 geh[4][4];
  {
    f32x4 acc[4][4]; ZACC(acc)
    bf16x8 bx1[4]; ldF<4>(bx1, plX, 4);
    gpass<4>(acc[0], Ahd, bX0, l, q);
    bf16x8 bx2[4]; ldF<4>(bx2, plX, 8);
    gpass<4>(acc[1], Ahd, bx1, l, q);
    bf16x8 bx3[4]; ldF<4>(bx3, plX, 12);
    gpass<4>(acc[2], Ahd, bx2, l, q);
    ldF<5>(g0, plD, 0);                               // first decoder l0 group
    gpass<4>(acc[3], Ahd, bx3, l, q);
#pragma unroll
    for (int g = 0; g < 4; ++g)
#pragma unroll
      for (int mt = 0; mt < 4; ++mt)
        geh[g][mt] = uint2{pk2(acc[g][mt][0], acc[g][mt][1]),
                           pk2(acc[g][mt][2], acc[g][mt][3])};
  }
  if (tid < M) {
    s_xc[tid] = pfx;                                  // x[:, 23]
    s_buf[tid * SB + 0] = (bf16_t)pfx;
#pragma unroll
    for (int e = 0; e < 7; ++e) s_buf[tid * SB + 3 + e] = (bf16_t)pfe[e];  // env[24]
  }
  const float b2i = (float)w[O_B2];
  const float b2o = (float)w[O_B2 + 1];
  const float b1i = (float)w[O_HEADP + jc];
  const float w2i = (float)w[O_HEADP + 128 + jc];
  const float b1o = (float)w[O_HEADP + 256 + jc];
  const float w2o = (float)w[O_HEADP + 384 + jc];
  __syncthreads();                                    // raw/xc ready; g0 drained

  // ================= decoder =================
#pragma unroll 1
  for (int s = 0; s < HOR; ++s) {
    const int t = T_CTX + s;
    f32x4 acc[4][4];
#pragma unroll
    for (int g = 0; g < 4; ++g)
#pragma unroll
      for (int mt = 0; mt < 4; ++mt)
        acc[g][mt] = f32x4{uplo(geh[g][mt].x), uphi(geh[g][mt].x),
                           uplo(geh[g][mt].y), uphi(geh[g][mt].y)};
    bf16x8 g1[5]; ldF<5>(g1, plD, 5);
    gpass<5>(acc[0], Al0, g0, l, q);
    bf16x8 g2[5]; ldF<5>(g2, plD, 10);
    gpass<5>(acc[1], Al0, g1, l, q);
    bf16x8 g3[5]; ldF<5>(g3, plD, 15);
    gpass<5>(acc[2], Al0, g2, l, q);
    bf16x8 u0[4]; ldF<4>(u0, plD, 20);
    gpass<5>(acc[3], Al0, g3, l, q);
    __syncthreads();                                  // Ba
    cell_up(acc, c0, s_buf + rowbase * SB + 32, s_bias + 1024, jc, q);
    bf16x8 u1[4]; ldF<4>(u1, plD, 24);
    __syncthreads();                                  // Bb
    ZACC(acc)
    gpass<4>(acc[0], Al1, u0, l, q);
    bf16x8 u2[4]; ldF<4>(u2, plD, 28);
    gpass<4>(acc[0], Al1 + 128, u1, l, q);
    bf16x8 u3[4]; ldF<4>(u3, plD, 32);
    gpass<4>(acc[1], Al1, u2, l, q);
    bf16x8 u4[4]; ldF<4>(u4, plD, 36);
    gpass<4>(acc[1], Al1 + 128, u3, l, q);
    bf16x8 u5[4]; ldF<4>(u5, plD, 40);
    gpass<4>(acc[2], Al1, u4, l, q);
    bf16x8 u6[4]; ldF<4>(u6, plD, 44);
    if (tid < M) {
      const int tn = (t + 1 < TT) ? t + 1 : t;
#pragma unroll
      for (int e = 0; e < 7; ++e) pfe[e] = (float)eb[e * TT + tn];
    }
    gpass<4>(acc[2], Al1 + 128, u5, l, q);
    bf16x8 u7[4]; ldF<4>(u7, plD, 48);
    gpass<4>(acc[3], Al1, u6, l, q);
    bf16x8 hbi[4]; ldF<4>(hbi, plD, 52);
    gpass<4>(acc[3], Al1 + 128, u7, l, q);
    __syncthreads();                                  // Bc
    cell_up(acc, c1, s_buf + rowbase * SB + 160, s_bias + 1536, jc, q);
    if (tid < 2 * M) s_red[tid] = 0.f;
    __syncthreads();                                  // Bd: h1 + s_red ready
    // ---- heads ----
    f32x4 hi[4], ho[4];
#pragma unroll
    for (int m = 0; m < 4; ++m) { hi[m] = f32x4{0.f,0.f,0.f,0.f}; ho[m] = f32x4{0.f,0.f,0.f,0.f}; }
    bf16x8 hbo[4]; ldF<4>(hbo, plD, 56);
    gpass<4>(hi, Ahd, hbi, l, q);
    ldF<5>(g0, plD, 0);                               // next step's l0 g0
    gpass<4>(ho, Ahd, hbo, l, q);
#pragma unroll
    for (int hd = 0; hd < 2; ++hd) {
      const float b1v = hd ? b1o : b1i;
      const float w2v = hd ? w2o : w2i;
#pragma unroll
      for (int mt = 0; mt < 4; ++mt)
#pragma unroll
        for (int r = 0; r < 4; ++r) {
          float val = fmaxf((hd ? ho[mt][r] : hi[mt][r]) + b1v, 0.f) * w2v;
          val += __shfl_xor(val, 1, 64);
          val += __shfl_xor(val, 2, 64);
          val += __shfl_xor(val, 4, 64);
          val += __shfl_xor(val, 8, 64);
          if (l == 0) atomicAdd(&s_red[hd * M + rowbase + mt * 16 + q * 4 + r], val);
        }
    }
    __syncthreads();                                  // Be: s_red complete
    if (tid < M) {
      float xc = s_xc[tid];
      float si = sigm(s_red[tid] + b2i);
      float so = sigm(s_red[M + tid] + b2o);
      float xn = xc + si - so * xc;
      s_xc[tid] = xn;
      out[(size_t)(node0 + tid) * HOR + s] = (T)xn;
      s_buf[tid * SB + 0] = (bf16_t)xn;
#pragma unroll
      for (int e = 0; e < 7; ++e) s_buf[tid * SB + 3 + e] = (bf16_t)pfe[e];
    }
    __syncthreads();                                  // Bf: raw + xc ready
  }
}

extern "C" void kernel_launch(void* const* d_in, const int* in_sizes, int n_in,
                              void* d_out, int out_size, void* d_ws, size_t ws_size,
                              hipStream_t stream) {
  (void)in_sizes; (void)n_in; (void)out_size; (void)ws_size;
  Ptrs P;
  for (int i = 0; i < 29; ++i) P.q[i] = d_in[i];
  int*    flag = (int*)d_ws;
  bf16_t* w    = (bf16_t*)d_ws;

  detect_kernel<<<1, 64, 0, stream>>>((const unsigned short*)d_in[4], flag);
  prep_kernel<<<256, 256, 0, stream>>>(P, w, flag);
  lstm_persist<float><<<GRID, NTH, 0, stream>>>(
      (const float*)d_in[0], (const float*)d_in[1], (const float*)d_in[2],
      w, flag, (float*)d_out);
  lstm_persist<__bf16><<<GRID, NTH, 0, stream>>>(
      (const __bf16*)d_in[0], (const __bf16*)d_in[1], (const __bf16*)d_in[2],
      w, flag, (__bf16*)d_out);
}

// Round 8
// 2938.306 us; speedup vs baseline: 2.2508x; 2.2508x over previous
//
#include <hip/hip_runtime.h>
#include <hip/hip_bf16.h>
#include <cstdint>
#include <cstddef>

typedef __bf16 bf16_t;
typedef bf16_t bf16x8 __attribute__((ext_vector_type(8)));
typedef bf16_t bf16x4 __attribute__((ext_vector_type(4)));
typedef float  f32x4  __attribute__((ext_vector_type(4)));

#define TT    64
#define T_CTX 24
#define HOR   40
#define SA    264     // LDS row stride (K=256 + 8 pad)
#define NTH   512     // 8 waves
#define GRID  256

#define MFMA __builtin_amdgcn_mfma_f32_16x16x32_bf16

// ---- ws layout (bf16-element offsets; flag int at elem 0) ----
#define O_PKE   16
#define O_PKD   (O_PKE + 262144)
#define O_PKX   (O_PKD + 294912)
#define O_BIAS  (O_PKX + 131072)
#define O_HEADP (O_BIAS + 2048)
#define O_WINE  (O_HEADP + 512)
#define O_WINN  (O_WINE + 1536)
#define O_B2    (O_WINN + 1536)
// phase-lock counters (dword index into ws): byte ofs = 2*(O_B2+2) = 1387556, /4:
#define O_CTR   346889

struct Ptrs { const void* q[29]; };

__device__ __forceinline__ float sigm(float x) {
  return __builtin_amdgcn_rcpf(1.f + __expf(-x));
}
__device__ __forceinline__ float tanh_(float x) {
  return 1.f - 2.f * __builtin_amdgcn_rcpf(1.f + __expf(2.f * x));
}
__device__ __forceinline__ unsigned pk2(float a, float b) {
  unsigned ua = __float_as_uint(a), ub = __float_as_uint(b);
  ua = (ua + 0x7fffu + ((ua >> 16) & 1u)) >> 16;
  ub = (ub + 0x7fffu + ((ub >> 16) & 1u)) >> 16;
  return ua | (ub << 16);
}
__device__ __forceinline__ float uplo(unsigned p){ return __uint_as_float(p << 16); }
__device__ __forceinline__ float uphi(unsigned p){ return __uint_as_float(p & 0xffff0000u); }

// Best-effort grid phase-lock. PERF-ONLY: aligns block phases for L2 stream
// locality. Escape valve (spin cap) => cannot deadlock, cannot affect results.
__device__ __forceinline__ void phase_lock(unsigned* ctr, unsigned target, int tid) {
  __syncthreads();
  if (tid == 0) {
    atomicAdd(ctr, 1u);                 // device-scope by default on CDNA
    int spins = 0;
    while (__hip_atomic_load(ctr, __ATOMIC_RELAXED, __HIP_MEMORY_SCOPE_AGENT) < target) {
      __builtin_amdgcn_s_sleep(2);
      if (++spins > 20000) break;       // ~1ms cap: escape valve
    }
  }
  __syncthreads();
}

// ================= dtype detector (validated r2) =================
__global__ void detect_kernel(const unsigned short* __restrict__ wsrc, int* __restrict__ flag)
{
  int tid = threadIdx.x;
  int wild = 0;
  for (int i = tid; i < 256; i += 64) {
    unsigned short b = wsrc[i];
    float v  = __uint_as_float(((unsigned)b) << 16);
    float av = fabsf(v);
    unsigned e = (b >> 7) & 0xff;
    if (av > 1000.f || e == 0xff || (((b & 0x7fff) != 0) && av < 1e-9f)) wild++;
  }
  for (int off = 32; off; off >>= 1) wild += __shfl_down(wild, off, 64);
  if (tid == 0) flag[0] = (wild > 16) ? 1 : 0;
}

// ================= prep (stream layout validated r3) =================
__global__ void prep_kernel(Ptrs P, bf16_t* __restrict__ wb, const int* __restrict__ flag)
{
  const bool f32 = (flag[0] != 0);
  const int gtid = blockIdx.x * blockDim.x + threadIdx.x;
  const int gsz  = gridDim.x * blockDim.x;
  auto rd = [&](const void* src, int i) -> float {
    return f32 ? ((const float*)src)[i] : (float)((const bf16_t*)src)[i];
  };

  if (gtid == 0) { ((unsigned*)wb)[O_CTR] = 0u; ((unsigned*)wb)[O_CTR + 1] = 0u; }

  for (int i = gtid; i < 262144; i += gsz) {
    int w = i >> 15, r = i & 32767, f = r >> 9, e = r & 511;
    int ln = e >> 3, j = e & 7;
    int seg = f >> 5, fk = f & 31, kt = fk >> 2, g = fk & 3;
    int row = g * 128 + w * 16 + (ln & 15);
    int col = kt * 32 + ((ln >> 4) << 3) + j;
    float v;
    if (seg == 0) v = (col < 128) ? rd(P.q[4], row * 128 + col) : rd(P.q[5], row * 128 + col - 128);
    else          v = (col < 128) ? rd(P.q[8], row * 128 + col) : rd(P.q[9], row * 128 + col - 128);
    wb[O_PKE + i] = (bf16_t)v;
  }
  for (int i = gtid; i < 294912; i += gsz) {
    int w = i / 36864, r = i - w * 36864, f = r >> 9, e = r & 511;
    int ln = e >> 3, j = e & 7;
    int colk = ((ln >> 4) << 3) + j;
    float v;
    if (f < 64) {
      int seg = f >> 5, fk = f & 31, kt = fk >> 2, g = fk & 3;
      int row = g * 128 + w * 16 + (ln & 15);
      int col = kt * 32 + colk;
      if (seg == 0) v = (col < 128) ? rd(P.q[13], row * 256 + col) : rd(P.q[14], row * 128 + col - 128);
      else          v = (col < 128) ? rd(P.q[17], row * 128 + col) : rd(P.q[18], row * 128 + col - 128);
    } else {
      int f2 = f - 64, h = f2 >> 2, kt = f2 & 3;
      int row = w * 16 + (ln & 15);
      int col = kt * 32 + colk;
      v = rd(h ? P.q[25] : P.q[21], row * 128 + col);
    }
    wb[O_PKD + i] = (bf16_t)v;
  }
  for (int i = gtid; i < 131072; i += gsz) {
    int w = i >> 14, r = i & 16383, f = r >> 9, e = r & 511;
    int ln = e >> 3, j = e & 7;
    int kt = f >> 2, g = f & 3;
    int row = g * 128 + w * 16 + (ln & 15);
    int col = kt * 32 + ((ln >> 4) << 3) + j;
    wb[O_PKX + i] = (bf16_t)rd(P.q[13], row * 256 + 128 + col);
  }
  for (int i = gtid; i < 512; i += gsz) {
    wb[O_BIAS + i]        = (bf16_t)(rd(P.q[6],  i) + rd(P.q[7],  i));
    wb[O_BIAS + 512 + i]  = (bf16_t)(rd(P.q[10], i) + rd(P.q[11], i));
    wb[O_BIAS + 1024 + i] = (bf16_t)(rd(P.q[15], i) + rd(P.q[16], i));
    wb[O_BIAS + 1536 + i] = (bf16_t)(rd(P.q[19], i) + rd(P.q[20], i));
  }
  for (int i = gtid; i < 128; i += gsz) {
    wb[O_HEADP + i]       = (bf16_t)rd(P.q[22], i);
    wb[O_HEADP + 128 + i] = (bf16_t)rd(P.q[23], i);
    wb[O_HEADP + 256 + i] = (bf16_t)rd(P.q[26], i);
    wb[O_HEADP + 384 + i] = (bf16_t)rd(P.q[27], i);
  }
  for (int i = gtid; i < 1536; i += gsz) {
    int cc = i / 12, j = i % 12;
    wb[O_WINE + i] = (j < 10) ? (bf16_t)rd(P.q[3],  cc * 10 + j) : (bf16_t)0.f;
    wb[O_WINN + i] = (j < 10) ? (bf16_t)rd(P.q[12], cc * 10 + j) : (bf16_t)0.f;
  }
  if (gtid == 0) {
    wb[O_B2]     = (bf16_t)rd(P.q[24], 0);
    wb[O_B2 + 1] = (bf16_t)rd(P.q[28], 0);
  }
}

// ================= main-kernel building blocks (r3, validated) =================
struct PreB { bf16x8 b[2][4]; };

__device__ __forceinline__ PreB preB(const bf16_t* __restrict__ pl) {
  PreB r;
#pragma unroll
  for (int p = 0; p < 2; ++p)
#pragma unroll
    for (int g = 0; g < 4; ++g)
      r.b[p][g] = *(const bf16x8*)(pl + (p * 4 + g) * 512);
  return r;
}

template<int NKT>
__device__ __forceinline__ void gemm_pk(f32x4 (&acc)[4][4], const bf16_t* __restrict__ As,
                                        const bf16_t* __restrict__ pl, const PreB& pre,
                                        int l, int q)
{
  bf16x8 bw[3][4];
#pragma unroll
  for (int g = 0; g < 4; ++g) { bw[0][g] = pre.b[0][g]; bw[1][g] = pre.b[1][g]; }
#pragma unroll
  for (int kt = 0; kt < NKT; ++kt) {
    bf16x8 a[4];
#pragma unroll
    for (int mt = 0; mt < 4; ++mt)
      a[mt] = *(const bf16x8*)(As + (mt * 16 + l) * SA + kt * 32 + q * 8);
    if (kt + 2 < NKT) {
#pragma unroll
      for (int g = 0; g < 4; ++g)
        bw[(kt + 2) % 3][g] = *(const bf16x8*)(pl + ((kt + 2) * 4 + g) * 512);
    }
#pragma unroll
    for (int g = 0; g < 4; ++g) {
      bf16x8 b = bw[kt % 3][g];
      acc[g][0] = MFMA(a[0], b, acc[g][0], 0, 0, 0);
      acc[g][1] = MFMA(a[1], b, acc[g][1], 0, 0, 0);
      acc[g][2] = MFMA(a[2], b, acc[g][2], 0, 0, 0);
      acc[g][3] = MFMA(a[3], b, acc[g][3], 0, 0, 0);
    }
  }
}

template<bool DUAL>
__device__ __forceinline__ void cell_up(f32x4 (&acc)[4][4], float (&c)[16],
                                        bf16_t* __restrict__ shb, bf16_t* __restrict__ sha,
                                        const bf16_t* __restrict__ bias,
                                        int wid, int l, int q)
{
  const int jc = wid * 16 + l;
  const float bi  = (float)bias[jc];
  const float bf_ = (float)bias[128 + jc];
  const float bg  = (float)bias[256 + jc];
  const float bo  = (float)bias[384 + jc];
#pragma unroll
  for (int mt = 0; mt < 4; ++mt) {
#pragma unroll
    for (int r = 0; r < 4; ++r) {
      float gi = acc[0][mt][r] + bi;
      float gf = acc[1][mt][r] + bf_;
      float gg = acc[2][mt][r] + bg;
      float go = acc[3][mt][r] + bo;
      float cn = sigm(gf) * c[mt * 4 + r] + sigm(gi) * tanh_(gg);
      float hh = sigm(go) * tanh_(cn);
      c[mt * 4 + r] = cn;
      const int row = mt * 16 + q * 4 + r;
      shb[row * SA + jc] = (bf16_t)hh;
      if (DUAL) sha[row * SA + jc] = (bf16_t)hh;
    }
  }
}

__device__ __forceinline__ void proj16(const float* v, const bf16_t* __restrict__ wbase,
                                       bf16_t* __restrict__ sx, int nd, int sub)
{
  bf16x8 o0, o1;
#pragma unroll
  for (int cc = 0; cc < 16; ++cc) {
    const bf16_t* wr = wbase + (sub * 16 + cc) * 12;
    bf16x4 w0 = *(const bf16x4*)(wr);
    bf16x4 w1 = *(const bf16x4*)(wr + 4);
    bf16x4 w2 = *(const bf16x4*)(wr + 8);
    float a = v[0] * (float)w0[0] + v[1] * (float)w0[1] + v[2] * (float)w0[2] + v[3] * (float)w0[3]
            + v[4] * (float)w1[0] + v[5] * (float)w1[1] + v[6] * (float)w1[2] + v[7] * (float)w1[3]
            + v[8] * (float)w2[0] + v[9] * (float)w2[1];
    if (cc < 8) o0[cc] = (bf16_t)a; else o1[cc - 8] = (bf16_t)a;
  }
  *(bf16x8*)(sx + nd * SA + sub * 16)     = o0;
  *(bf16x8*)(sx + nd * SA + sub * 16 + 8) = o1;
}

// ================= persistent LSTM kernel =================
template<typename T>
__global__ __launch_bounds__(NTH, 1) void lstm_persist(
    const T* __restrict__ x, const T* __restrict__ coords, const T* __restrict__ env,
    const bf16_t* __restrict__ w, const int* __restrict__ flag, T* __restrict__ out,
    unsigned* ctr)
{
  const bool want_f32 = (sizeof(T) == 4);
  if ((flag[0] != 0) != want_f32) return;

  __shared__ __align__(16) bf16_t bufA[64 * SA];
  __shared__ __align__(16) bf16_t bufB[64 * SA];
  __shared__ __align__(16) bf16_t s_win[2 * 128 * 12];
  __shared__ __align__(16) bf16_t s_bias[4 * 512];
  __shared__ float s_red[128];
  __shared__ float s_xc[64];

  const int tid  = threadIdx.x;
  const int wid  = tid >> 6;
  const int lane = tid & 63;
  const int l    = tid & 15;
  const int q    = (tid & 63) >> 4;
  const int node0 = blockIdx.x * 64;
  const int nd  = tid >> 3;
  const int sub = tid & 7;

  const bf16_t* plE0 = w + O_PKE + wid * 32768 + lane * 8;
  const bf16_t* plE1 = plE0 + 16384;
  const bf16_t* plD0 = w + O_PKD + wid * 36864 + lane * 8;
  const bf16_t* plD1 = plD0 + 16384;
  const bf16_t* plH  = plD0 + 32768;
  const bf16_t* plX  = w + O_PKX + wid * 16384 + lane * 8;

  for (int i = tid; i < 2048; i += NTH) s_bias[i] = w[O_BIAS + i];
  for (int i = tid; i < 3072; i += NTH) s_win[i]  = w[O_WINE + i];
  for (int i = tid; i < 64 * SA; i += NTH) { bufA[i] = (bf16_t)0.f; bufB[i] = (bf16_t)0.f; }

  const float cx = (float)coords[(size_t)(node0 + nd) * 2 + 0];
  const float cy = (float)coords[(size_t)(node0 + nd) * 2 + 1];

  float c0[16], c1[16];
#pragma unroll
  for (int i = 0; i < 16; ++i) { c0[i] = 0.f; c1[i] = 0.f; }

  unsigned ep = 0;
  PreB pA = preB(plE0);
  __syncthreads();

  // ================= encoder =================
#pragma unroll 1
  for (int t = 0; t < T_CTX; ++t) {
    float v[10];
    v[0] = (float)x[(size_t)(node0 + nd) * TT + t];
    v[1] = cx; v[2] = cy;
#pragma unroll
    for (int e = 0; e < 7; ++e)
      v[3 + e] = (float)env[((size_t)(node0 + nd) * 7 + e) * TT + t];
    proj16(v, s_win, bufA, nd, sub);
    __syncthreads();                           // E1: bufA ready

    f32x4 acc[4][4];
#pragma unroll
    for (int g = 0; g < 4; ++g)
#pragma unroll
      for (int mt = 0; mt < 4; ++mt) acc[g][mt] = f32x4{0.f, 0.f, 0.f, 0.f};
    gemm_pk<8>(acc, bufA, plE0, pA, l, q);
    PreB pC = preB(plE1);
    __syncthreads();                           // E2: bufA consumed
    cell_up<true>(acc, c0, bufB, bufA + 128, s_bias, wid, l, q);
    __syncthreads();                           // E3: bufB[0:128] ready

#pragma unroll
    for (int g = 0; g < 4; ++g)
#pragma unroll
      for (int mt = 0; mt < 4; ++mt) acc[g][mt] = f32x4{0.f, 0.f, 0.f, 0.f};
    gemm_pk<8>(acc, bufB, plE1, pC, l, q);
    pA = preB((t < T_CTX - 1) ? plE0 : plX);
    __syncthreads();                           // E4: bufB consumed
    cell_up<false>(acc, c1, bufB + 128, nullptr, s_bias + 512, wid, l, q);

    ++ep; phase_lock(ctr, ep * GRID, tid);     // keep XCD-mates streaming together
  }
  __syncthreads();                             // enc-final h1 visible

  // ---- enc_state @ inWih[:,128:256]^T once ----
  uint2 geh[4][4];
  {
    f32x4 acc[4][4];
#pragma unroll
    for (int g = 0; g < 4; ++g)
#pragma unroll
      for (int mt = 0; mt < 4; ++mt) acc[g][mt] = f32x4{0.f, 0.f, 0.f, 0.f};
    gemm_pk<4>(acc, bufB + 128, plX, pA, l, q);
#pragma unroll
    for (int g = 0; g < 4; ++g)
#pragma unroll
      for (int mt = 0; mt < 4; ++mt)
        geh[g][mt] = uint2{pk2(acc[g][mt][0], acc[g][mt][1]),
                           pk2(acc[g][mt][2], acc[g][mt][3])};
  }
  if (tid < 64) s_xc[tid] = (float)x[(size_t)(node0 + tid) * TT + (T_CTX - 1)];
  const float b2i = (float)w[O_B2];
  const float b2o = (float)w[O_B2 + 1];
  const float b1i = (float)w[O_HEADP + wid * 16 + l];
  const float w2i = (float)w[O_HEADP + 128 + wid * 16 + l];
  const float b1o = (float)w[O_HEADP + 256 + wid * 16 + l];
  const float w2o = (float)w[O_HEADP + 384 + wid * 16 + l];
  pA = preB(plD0);
  __syncthreads();                             // s_xc ready

  // ================= decoder =================
#pragma unroll 1
  for (int s = 0; s < HOR; ++s) {
    const int t = T_CTX + s;
    float v[10];
    v[0] = s_xc[nd];
    v[1] = cx; v[2] = cy;
#pragma unroll
    for (int e = 0; e < 7; ++e)
      v[3 + e] = (float)env[((size_t)(node0 + nd) * 7 + e) * TT + t];
    proj16(v, s_win + 1536, bufA, nd, sub);
    __syncthreads();                           // S1: bufA ready

    f32x4 acc[4][4];
#pragma unroll
    for (int g = 0; g < 4; ++g)
#pragma unroll
      for (int mt = 0; mt < 4; ++mt)
        acc[g][mt] = f32x4{uplo(geh[g][mt].x), uphi(geh[g][mt].x),
                           uplo(geh[g][mt].y), uphi(geh[g][mt].y)};
    gemm_pk<8>(acc, bufA, plD0, pA, l, q);
    PreB pC = preB(plD1);
    __syncthreads();                           // S2: bufA consumed
    cell_up<true>(acc, c0, bufB, bufA + 128, s_bias + 1024, wid, l, q);
    __syncthreads();                           // S3: bufB[0:128] ready

#pragma unroll
    for (int g = 0; g < 4; ++g)
#pragma unroll
      for (int mt = 0; mt < 4; ++mt) acc[g][mt] = f32x4{0.f, 0.f, 0.f, 0.f};
    gemm_pk<8>(acc, bufB, plD1, pC, l, q);
    bf16x8 hb[8];
#pragma unroll
    for (int f = 0; f < 8; ++f) hb[f] = *(const bf16x8*)(plH + f * 512);
    __syncthreads();                           // S4: bufB consumed
    cell_up<false>(acc, c1, bufB + 128, nullptr, s_bias + 1536, wid, l, q);
    if (tid < 128) s_red[tid] = 0.f;
    pA = preB(plD0);
    __syncthreads();                           // S5: h1 + s_red ready

    // ---- heads ----
    f32x4 hacc[2][4];
#pragma unroll
    for (int hd = 0; hd < 2; ++hd)
#pragma unroll
      for (int mt = 0; mt < 4; ++mt) hacc[hd][mt] = f32x4{0.f, 0.f, 0.f, 0.f};
#pragma unroll
    for (int kt = 0; kt < 4; ++kt) {
      bf16x8 a[4];
#pragma unroll
      for (int mt = 0; mt < 4; ++mt)
        a[mt] = *(const bf16x8*)(bufB + 128 + (mt * 16 + l) * SA + kt * 32 + q * 8);
#pragma unroll
      for (int mt = 0; mt < 4; ++mt) {
        hacc[0][mt] = MFMA(a[mt], hb[kt],     hacc[0][mt], 0, 0, 0);
        hacc[1][mt] = MFMA(a[mt], hb[4 + kt], hacc[1][mt], 0, 0, 0);
      }
    }
#pragma unroll
    for (int hd = 0; hd < 2; ++hd) {
      const float b1v = hd ? b1o : b1i;
      const float w2v = hd ? w2o : w2i;
#pragma unroll
      for (int mt = 0; mt < 4; ++mt)
#pragma unroll
        for (int r = 0; r < 4; ++r) {
          float val = fmaxf(hacc[hd][mt][r] + b1v, 0.f) * w2v;
          val += __shfl_xor(val, 1, 64);
          val += __shfl_xor(val, 2, 64);
          val += __shfl_xor(val, 4, 64);
          val += __shfl_xor(val, 8, 64);
          if (l == 0) atomicAdd(&s_red[hd * 64 + mt * 16 + q * 4 + r], val);
        }
    }
    __syncthreads();                           // S6: s_red complete
    if (tid < 64) {
      float xc = s_xc[tid];
      float si = sigm(s_red[tid] + b2i);
      float so = sigm(s_red[64 + tid] + b2o);
      float xn = xc + si - so * xc;
      s_xc[tid] = xn;
      out[(size_t)(node0 + tid) * HOR + s] = (T)xn;
    }
    __syncthreads();                           // S7: s_xc stable

    ++ep; phase_lock(ctr, ep * GRID, tid);
  }
}

extern "C" void kernel_launch(void* const* d_in, const int* in_sizes, int n_in,
                              void* d_out, int out_size, void* d_ws, size_t ws_size,
                              hipStream_t stream) {
  (void)in_sizes; (void)n_in; (void)out_size; (void)ws_size;
  Ptrs P;
  for (int i = 0; i < 29; ++i) P.q[i] = d_in[i];
  int*      flag = (int*)d_ws;
  bf16_t*   w    = (bf16_t*)d_ws;
  unsigned* ctr  = (unsigned*)d_ws + O_CTR;

  detect_kernel<<<1, 64, 0, stream>>>((const unsigned short*)d_in[4], flag);
  prep_kernel<<<256, 256, 0, stream>>>(P, w, flag);
  lstm_persist<float><<<GRID, NTH, 0, stream>>>(
      (const float*)d_in[0], (const float*)d_in[1], (const float*)d_in[2],
      w, flag, (float*)d_out, ctr);
  lstm_persist<__bf16><<<GRID, NTH, 0, stream>>>(
      (const __bf16*)d_in[0], (const __bf16*)d_in[1], (const __bf16*)d_in[2],
      w, flag, (__bf16*)d_out, ctr + 1);
}